// Round 5
// baseline (1316.729 us; speedup 1.0000x reference)
//
#include <hip/hip_runtime.h>
#include <cstddef>
#include <cstdint>
#include <cmath>

#define NPIX     12288
#define NBUCKETS 32
#define IN_DIM   32
#define PROJ_IN  1056
#define PROJ_OUT 256
#define OUT_DIM  128
#define LN_EPS   1e-5f
#define NBATCH   4

#define ROWS   (NBATCH * NPIX)        // 49152
#define GCELLS (ROWS * NBUCKETS)      // 1,572,864

#define SCAN_CHUNK 2048
#define NBLK_SCAN  (GCELLS / SCAN_CHUNK)   // 768

#define W1RECS (33 * 16 * 64)   // 33792 fragment records (16B each)
#define W2RECS (8 * 8 * 64)     // 4096

typedef __attribute__((ext_vector_type(8))) short bf16x8;
typedef __attribute__((ext_vector_type(4))) float f32x4;

// ---------------------------------------------------------------------------
// K0: swizzle W1/W2 into MFMA B-fragment-linear order (hi/lo split-bf16).
// Record r = ((s*NF + n0)*64 + l): 8 bf16, elem j = W[(s*32+(l>>4)*8+j)][n0*16+(l&15)]
// ---------------------------------------------------------------------------
__device__ inline unsigned bf16_rne_bits(float v) {
    unsigned u = __float_as_uint(v);
    return (u + 0x7FFFu + ((u >> 16) & 1u)) >> 16;
}

__global__ __launch_bounds__(256)
void swz_kernel(const float* __restrict__ W1, const float* __restrict__ W2,
                bf16x8* __restrict__ w1h, bf16x8* __restrict__ w1l,
                bf16x8* __restrict__ w2h, bf16x8* __restrict__ w2l)
{
    const int T = blockIdx.x * 256 + threadIdx.x;
    if (T < W1RECS) {
        const int l = T & 63, n0 = (T >> 6) & 15, s = T >> 10;
        const int col  = n0 * 16 + (l & 15);
        const int krow = s * 32 + (l >> 4) * 8;
        bf16x8 vh, vl;
#pragma unroll
        for (int j = 0; j < 8; ++j) {
            const float v = W1[(size_t)(krow + j) * PROJ_OUT + col];
            const unsigned hb = bf16_rne_bits(v);
            const float hf = __uint_as_float(hb << 16);
            const unsigned lb = bf16_rne_bits(v - hf);
            vh[j] = (short)hb; vl[j] = (short)lb;
        }
        w1h[T] = vh; w1l[T] = vl;
    } else if (T < W1RECS + W2RECS) {
        const int T2 = T - W1RECS;
        const int l = T2 & 63, n0 = (T2 >> 6) & 7, s2 = T2 >> 9;
        const int col  = n0 * 16 + (l & 15);
        const int krow = s2 * 32 + (l >> 4) * 8;
        bf16x8 vh, vl;
#pragma unroll
        for (int j = 0; j < 8; ++j) {
            const float v = W2[(size_t)(krow + j) * OUT_DIM + col];
            const unsigned hb = bf16_rne_bits(v);
            const float hf = __uint_as_float(hb << 16);
            const unsigned lb = bf16_rne_bits(v - hf);
            vh[j] = (short)hb; vl[j] = (short)lb;
        }
        w2h[T2] = vh; w2l[T2] = vl;
    }
}

// ---------------------------------------------------------------------------
// K1: flat index + histogram + within-cell rank (atomic return value).
// ---------------------------------------------------------------------------
__global__ __launch_bounds__(256)
void flat_hist_kernel(const int* __restrict__ bidx, const int* __restrict__ pix,
                      const int* __restrict__ bucket, int* __restrict__ flat,
                      int* __restrict__ rank, int* __restrict__ cnt, int N)
{
    int p = blockIdx.x * 256 + threadIdx.x;
    if (p >= N) return;
    int f = bidx[p] * (NPIX * NBUCKETS) + pix[p] * NBUCKETS + bucket[p];
    flat[p] = f;
    rank[p] = atomicAdd(&cnt[f], 1);
}

// ---------------------------------------------------------------------------
// K2a: per-chunk (2048) reduction of counts -> partials[NBLK_SCAN]
// ---------------------------------------------------------------------------
__global__ __launch_bounds__(256)
void scan_reduce_kernel(const int* __restrict__ cnt, int* __restrict__ partials)
{
    __shared__ int wsum[4];
    const int b = blockIdx.x, t = threadIdx.x;
    const int4* src = reinterpret_cast<const int4*>(cnt + (size_t)b * SCAN_CHUNK);
    int4 v0 = src[t * 2], v1 = src[t * 2 + 1];
    int s = v0.x + v0.y + v0.z + v0.w + v1.x + v1.y + v1.z + v1.w;
#pragma unroll
    for (int off = 32; off; off >>= 1) s += __shfl_xor(s, off);
    if ((t & 63) == 0) wsum[t >> 6] = s;
    __syncthreads();
    if (t == 0) partials[b] = wsum[0] + wsum[1] + wsum[2] + wsum[3];
}

// ---------------------------------------------------------------------------
// K2b: exclusive scan of the 768 partials in place. One wave (64 thr x 12).
// ---------------------------------------------------------------------------
__global__ void scan_mid_kernel(int* __restrict__ partials)
{
    const int t = threadIdx.x;   // 0..63
    int v[12]; int s = 0;
#pragma unroll
    for (int i = 0; i < 12; ++i) { v[i] = partials[t * 12 + i]; s += v[i]; }
    int inc = s;
#pragma unroll
    for (int d = 1; d < 64; d <<= 1) { int o = __shfl_up(inc, d); if (t >= d) inc += o; }
    int base = inc - s;
#pragma unroll
    for (int i = 0; i < 12; ++i) { int x = v[i]; partials[t * 12 + i] = base; base += x; }
}

// ---------------------------------------------------------------------------
// K2c: write exclusive offsets.
// ---------------------------------------------------------------------------
__global__ __launch_bounds__(256)
void scan_write_kernel(const int* __restrict__ partials, const int* __restrict__ cnt,
                       int* __restrict__ offs)
{
    __shared__ int wbase[4];
    const int b = blockIdx.x, t = threadIdx.x;
    const int lane = t & 63, w = t >> 6;
    const int4* src = reinterpret_cast<const int4*>(cnt + (size_t)b * SCAN_CHUNK);
    int4 v0 = src[t * 2], v1 = src[t * 2 + 1];
    int a[8] = { v0.x, v0.y, v0.z, v0.w, v1.x, v1.y, v1.z, v1.w };
    int s = 0;
#pragma unroll
    for (int i = 0; i < 8; ++i) s += a[i];
    int inc = s;
#pragma unroll
    for (int d = 1; d < 64; d <<= 1) { int o = __shfl_up(inc, d); if (lane >= d) inc += o; }
    if (lane == 63) wbase[w] = inc;
    __syncthreads();
    int wb = 0;
    for (int i = 0; i < w; ++i) wb += wbase[i];
    int base = partials[b] + wb + (inc - s);
    const int idx0 = b * SCAN_CHUNK + t * 8;
#pragma unroll
    for (int i = 0; i < 8; ++i) { offs[idx0 + i] = base; base += a[i]; }
    if (b == (int)gridDim.x - 1 && t == 255) offs[GCELLS] = base;
}

// ---------------------------------------------------------------------------
// K3: reorder point indices into cell-grouped order[] (NO atomics).
// ---------------------------------------------------------------------------
__global__ __launch_bounds__(256)
void reorder_kernel(const int* __restrict__ flat, const int* __restrict__ rank,
                    const int* __restrict__ offs, int* __restrict__ order, int N)
{
    int p = blockIdx.x * 256 + threadIdx.x;
    if (p >= N) return;
    order[offs[flat[p]] + rank[p]] = p;
}

// ---------------------------------------------------------------------------
// Fallback: write zeros to d_out if ws is too small (graceful fail).
// ---------------------------------------------------------------------------
__global__ void zero_out_kernel(float* __restrict__ out, size_t n)
{
    size_t i = (size_t)blockIdx.x * blockDim.x + threadIdx.x;
    if (i < n) out[i] = 0.f;
}

// ---------------------------------------------------------------------------
// Fused MFMA MLP. 256 threads = 4 waves; block = 64 rows; wave = 16-row strip.
// GEMM1: split-bf16 MFMA 16x16x32, A gathered per-lane from feats (mean),
// B streamed fragment-linear from L2 (pre-swizzled W1). LN+SiLU in-register.
// GEMM2 via wave-local LDS fragment buffer. No per-kstep barriers.
// ---------------------------------------------------------------------------
__global__ __launch_bounds__(256, 3)
void fused_mlp_mfma(const float* __restrict__ feats,
                    const int*   __restrict__ order_g,
                    const int*   __restrict__ offs_g,
                    const bf16x8* __restrict__ w1h, const bf16x8* __restrict__ w1l,
                    const bf16x8* __restrict__ w2h, const bf16x8* __restrict__ w2l,
                    const float* __restrict__ b1,   const float* __restrict__ ln_g,
                    const float* __restrict__ ln_b, const float* __restrict__ b2,
                    float* __restrict__ out)
{
    // offsT[row r][bucket b] = offs_g[(row0+r)*32 + b], b=0..32 (33 per row).
    __shared__ int offsT[64 * 33];                    // 8448 B
    __shared__ __align__(16) short hfH[4][2048];      // per-wave A2-frag hi (4KB each)
    __shared__ __align__(16) short hfL[4][2048];      // per-wave A2-frag lo

    const int t  = threadIdx.x;
    const int w  = t >> 6;          // wave 0..3
    const int l  = t & 63;          // lane
    const int g  = l >> 4;          // 0..3 (k-group / C row-group)
    const int li = l & 15;
    const int row0 = blockIdx.x * 64;
    const int rl = w * 16 + li;     // A-operand row (block-local)

    for (int i = t; i < 64 * 33; i += 256) {
        const int r = i / 33, b = i - r * 33;
        offsT[i] = offs_g[(size_t)row0 * 32 + r * 32 + b];
    }
    __syncthreads();

    f32x4 acc[16];
#pragma unroll
    for (int n0 = 0; n0 < 16; ++n0) acc[n0] = (f32x4){0.f, 0.f, 0.f, 0.f};

    const float4* feats4 = reinterpret_cast<const float4*>(feats);

    // ---------------- GEMM1: 33 k-steps of 32 ----------------
    for (int s = 0; s < 33; ++s) {
        float m[8];
        if (s < 32) {
            const int start = offsT[rl * 33 + s];
            const int end   = offsT[rl * 33 + s + 1];
            float4 a0 = make_float4(0.f, 0.f, 0.f, 0.f);
            float4 a1 = make_float4(0.f, 0.f, 0.f, 0.f);
            for (int j2 = start; j2 < end; ++j2) {
                const int idx = order_g[j2];
                const float4 p0 = feats4[(size_t)idx * 8 + g * 2];
                const float4 p1 = feats4[(size_t)idx * 8 + g * 2 + 1];
                a0.x += p0.x; a0.y += p0.y; a0.z += p0.z; a0.w += p0.w;
                a1.x += p1.x; a1.y += p1.y; a1.z += p1.z; a1.w += p1.w;
            }
            const float inv = (end > start) ? 1.f / (float)(end - start) : 0.f;
            m[0] = a0.x * inv; m[1] = a0.y * inv; m[2] = a0.z * inv; m[3] = a0.w * inv;
            m[4] = a1.x * inv; m[5] = a1.y * inv; m[6] = a1.z * inv; m[7] = a1.w * inv;
        } else {   // has_obs tail: k = 1024 + (g*8+j) -> bucket g*8+j
#pragma unroll
            for (int j = 0; j < 8; ++j) {
                const int b = g * 8 + j;
                m[j] = (offsT[rl * 33 + b + 1] > offsT[rl * 33 + b]) ? 1.f : 0.f;
            }
        }
        // truncation split: a = hi + lo, residual <= 2^-16 |a|
        bf16x8 ah, al;
#pragma unroll
        for (int j = 0; j < 8; ++j) {
            const unsigned u = __float_as_uint(m[j]);
            ah[j] = (short)(u >> 16);
            const float rlo = m[j] - __uint_as_float(u & 0xFFFF0000u);
            al[j] = (short)(__float_as_uint(rlo) >> 16);
        }
        const int base = (s * 16) * 64 + l;
        if (s < 32) {
#pragma unroll 4
            for (int n0 = 0; n0 < 16; ++n0) {
                const bf16x8 bh = w1h[base + n0 * 64];
                const bf16x8 bl = w1l[base + n0 * 64];
                acc[n0] = __builtin_amdgcn_mfma_f32_16x16x32_bf16(ah, bh, acc[n0], 0, 0, 0);
                acc[n0] = __builtin_amdgcn_mfma_f32_16x16x32_bf16(ah, bl, acc[n0], 0, 0, 0);
                acc[n0] = __builtin_amdgcn_mfma_f32_16x16x32_bf16(al, bh, acc[n0], 0, 0, 0);
            }
        } else {   // A exact in bf16 (0/1): lo == 0
#pragma unroll 4
            for (int n0 = 0; n0 < 16; ++n0) {
                const bf16x8 bh = w1h[base + n0 * 64];
                const bf16x8 bl = w1l[base + n0 * 64];
                acc[n0] = __builtin_amdgcn_mfma_f32_16x16x32_bf16(ah, bh, acc[n0], 0, 0, 0);
                acc[n0] = __builtin_amdgcn_mfma_f32_16x16x32_bf16(ah, bl, acc[n0], 0, 0, 0);
            }
        }
    }

    // ---------------- bias + LayerNorm + SiLU (in-register) ----------------
    // C layout: col = n0*16+li, row (strip-local) = g*4 + r.
    float sum[4] = {0.f, 0.f, 0.f, 0.f}, sq[4] = {0.f, 0.f, 0.f, 0.f};
#pragma unroll
    for (int n0 = 0; n0 < 16; ++n0) {
        const float bb = b1[n0 * 16 + li];
#pragma unroll
        for (int r = 0; r < 4; ++r) {
            const float v = acc[n0][r] + bb;
            acc[n0][r] = v;
            sum[r] += v;
            sq[r] = fmaf(v, v, sq[r]);
        }
    }
#pragma unroll
    for (int off = 1; off < 16; off <<= 1) {
#pragma unroll
        for (int r = 0; r < 4; ++r) {
            sum[r] += __shfl_xor(sum[r], off);
            sq[r]  += __shfl_xor(sq[r], off);
        }
    }
    float mu[4], rs[4];
#pragma unroll
    for (int r = 0; r < 4; ++r) {
        mu[r] = sum[r] * (1.f / 256.f);
        const float var = sq[r] * (1.f / 256.f) - mu[r] * mu[r];
        rs[r] = rsqrtf(var + LN_EPS);
    }
#pragma unroll
    for (int n0 = 0; n0 < 16; ++n0) {
        const float gg = ln_g[n0 * 16 + li];
        const float eb = ln_b[n0 * 16 + li];
#pragma unroll
        for (int r = 0; r < 4; ++r) {
            float v = fmaf((acc[n0][r] - mu[r]) * rs[r], gg, eb);
            v = v / (1.f + __expf(-v));
            acc[n0][r] = v;
        }
    }

    // ---------------- GEMM2 (256 -> 128), two k-half passes ----------------
    f32x4 acc2[8];
#pragma unroll
    for (int n0 = 0; n0 < 8; ++n0) acc2[n0] = (f32x4){0.f, 0.f, 0.f, 0.f};

    for (int p = 0; p < 2; ++p) {
        // write this half's h cols as A2 fragments (wave-local, no barrier)
#pragma unroll
        for (int q = 0; q < 8; ++q) {
            const int n0 = p * 8 + q;
            const int c = n0 * 16 + li;            // h col 0..255
            const int s2l = (c >> 5) & 3;          // local kstep
            const int kk = c & 31;
            const int wbase = s2l * 512 + (kk >> 3) * 128 + (kk & 7);
#pragma unroll
            for (int r = 0; r < 4; ++r) {
                const float v = acc[n0][r];
                const unsigned u = __float_as_uint(v);
                const short hi = (short)(u >> 16);
                const float rlo = v - __uint_as_float(u & 0xFFFF0000u);
                const short lo = (short)(__float_as_uint(rlo) >> 16);
                const int a = wbase + (g * 4 + r) * 8;
                hfH[w][a] = hi;
                hfL[w][a] = lo;
            }
        }
        // consume: 4 local ksteps
#pragma unroll
        for (int s2l = 0; s2l < 4; ++s2l) {
            const bf16x8 a2h = *reinterpret_cast<const bf16x8*>(&hfH[w][(s2l * 64 + l) * 8]);
            const bf16x8 a2l = *reinterpret_cast<const bf16x8*>(&hfL[w][(s2l * 64 + l) * 8]);
            const int b2base = ((p * 4 + s2l) * 8) * 64 + l;
#pragma unroll 4
            for (int n0 = 0; n0 < 8; ++n0) {
                const bf16x8 bh = w2h[b2base + n0 * 64];
                const bf16x8 bl = w2l[b2base + n0 * 64];
                acc2[n0] = __builtin_amdgcn_mfma_f32_16x16x32_bf16(a2h, bh, acc2[n0], 0, 0, 0);
                acc2[n0] = __builtin_amdgcn_mfma_f32_16x16x32_bf16(a2h, bl, acc2[n0], 0, 0, 0);
                acc2[n0] = __builtin_amdgcn_mfma_f32_16x16x32_bf16(a2l, bh, acc2[n0], 0, 0, 0);
            }
        }
    }

    // ---------------- output ----------------
#pragma unroll
    for (int n0 = 0; n0 < 8; ++n0) {
        const float bb = b2[n0 * 16 + li];
#pragma unroll
        for (int r = 0; r < 4; ++r) {
            out[(size_t)(row0 + w * 16 + g * 4 + r) * OUT_DIM + n0 * 16 + li] = acc2[n0][r] + bb;
        }
    }
}

// ---------------------------------------------------------------------------
extern "C" void kernel_launch(void* const* d_in, const int* in_sizes, int n_in,
                              void* d_out, int out_size, void* d_ws, size_t ws_size,
                              hipStream_t stream)
{
    const float* feats  = (const float*)d_in[0];
    const int*   bidx   = (const int*)d_in[1];
    const int*   pix    = (const int*)d_in[2];
    const int*   bucket = (const int*)d_in[3];
    // d_in[4] = nbatch scalar (== 4, hardcoded as NBATCH)
    const float* W1   = (const float*)d_in[5];
    const float* b1   = (const float*)d_in[6];
    const float* ln_g = (const float*)d_in[7];
    const float* ln_b = (const float*)d_in[8];
    const float* W2   = (const float*)d_in[9];
    const float* b2   = (const float*)d_in[10];
    float* out = (float*)d_out;

    const int N = in_sizes[1];   // 2,000,000

    // workspace layout
    int* flat     = (int*)d_ws;               // N
    int* rank     = flat + N;                 // N
    int* order    = rank + N;                 // N
    int* cnt      = order + N;                // GCELLS
    int* offs     = cnt + GCELLS;             // GCELLS + 1
    int* partials = offs + GCELLS + 1;        // NBLK_SCAN
    const size_t int_bytes = ((size_t)3 * N + 2 * GCELLS + 1 + NBLK_SCAN) * sizeof(int);
    const size_t swz_off = (int_bytes + 15) & ~(size_t)15;
    bf16x8* w1h = (bf16x8*)((char*)d_ws + swz_off);
    bf16x8* w1l = w1h + W1RECS;
    bf16x8* w2h = w1l + W1RECS;
    bf16x8* w2l = w2h + W2RECS;
    const size_t ws_needed = swz_off + (size_t)(2 * W1RECS + 2 * W2RECS) * 16;

    if (ws_size < ws_needed) {
        size_t n = (size_t)out_size;
        zero_out_kernel<<<(unsigned)((n + 255) / 256), 256, 0, stream>>>(out, n);
        return;
    }

    hipMemsetAsync(cnt, 0, (size_t)GCELLS * sizeof(int), stream);

    swz_kernel<<<(W1RECS + W2RECS + 255) / 256, 256, 0, stream>>>(W1, W2, w1h, w1l, w2h, w2l);

    const int pgrid = (N + 255) / 256;
    flat_hist_kernel<<<pgrid, 256, 0, stream>>>(bidx, pix, bucket, flat, rank, cnt, N);
    scan_reduce_kernel<<<NBLK_SCAN, 256, 0, stream>>>(cnt, partials);
    scan_mid_kernel<<<1, 64, 0, stream>>>(partials);
    scan_write_kernel<<<NBLK_SCAN, 256, 0, stream>>>(partials, cnt, offs);
    reorder_kernel<<<pgrid, 256, 0, stream>>>(flat, rank, offs, order, N);

    fused_mlp_mfma<<<ROWS / 64, 256, 0, stream>>>(feats, order, offs,
                                                  w1h, w1l, w2h, w2l,
                                                  b1, ln_g, ln_b, b2, out);
}